// Round 7
// baseline (271.564 us; speedup 1.0000x reference)
//
#include <hip/hip_runtime.h>
#include <stdint.h>

// ---------------------------------------------------------------------------
// SelfAttention: out = softmax((x Wq^T)(x Wk^T)^T / sqrt(E)) (x Wv^T)
// B=4, S=2048, E=1024. bf16 MFMA, fp32 accumulate.
// R14 = R13 resubmitted (previous bench: container infra failure, kernel
// never ran; bounds/bijectivity/vmcnt re-audited OK).
// R13: R12 engine (3-stage ring, conflict-free XOR-permuted LDS, 71.7 us)
// with a templated tile N-width.  Diagnosis: QKV (3 resident blocks/CU)
// hits 715 TF; scores (4 total/CU) and PV (2 total/CU) sit at 477 TF --
// latency-bound from too little block-level TLP, not schedule (R8-R11
// falsified) nor conflicts (R12 fixed, +4%).  Fix: BN=64 for scores+PV ->
// LDS 36 KB -> 4 blocks/CU (16 waves), exact rounds: scores 2048 blk = 2,
// PV 1024 blk = 1.  Ring/vmcnt discipline unchanged (3 loads/tile ->
// steady wait vmcnt(3)).  QKV stays 128x128 (best measured).
// Dispatches: cast, QKV, scores, softmax, PV.
// ---------------------------------------------------------------------------

typedef __attribute__((ext_vector_type(8))) short bf16x8;   // 8 bf16 = 4 VGPRs
typedef __attribute__((ext_vector_type(4))) float f32x4;

__device__ __forceinline__ float bf2f(uint16_t u) {
    return __uint_as_float(((uint32_t)u) << 16);
}
__device__ __forceinline__ uint16_t f2bf(float f) {
    uint32_t u = __float_as_uint(f);
    uint32_t r = u + 0x7FFFu + ((u >> 16) & 1u);   // RNE
    return (uint16_t)(r >> 16);
}

// async global -> LDS, 16 bytes per lane (wave-uniform base + lane*16)
__device__ __forceinline__ void gll16(const void* g, void* l) {
    __builtin_amdgcn_global_load_lds(
        (const __attribute__((address_space(1))) uint32_t*)g,
        (__attribute__((address_space(3))) uint32_t*)l,
        16, 0, 0);
}

// ---- fused cast: x (NX4 float4s) then stacked Wq|Wk|Wv (NW4 each) ---------
__global__ __launch_bounds__(256) void cast_all(const float* __restrict__ x,
                                                const float* __restrict__ Wq,
                                                const float* __restrict__ Wk,
                                                const float* __restrict__ Wv,
                                                uint16_t* __restrict__ xb,
                                                uint16_t* __restrict__ wqkvb,
                                                int NX4, int NW4) {
    int i = blockIdx.x * 256 + threadIdx.x;
    const float* src;
    uint16_t* dst;
    int off;
    if (i < NX4) {
        src = x; dst = xb; off = i;
    } else {
        int j = i - NX4;
        if (j >= 3 * NW4) return;
        int which = j / NW4;              // 0,1,2
        off = j - which * NW4;
        src = (which == 0) ? Wq : (which == 1) ? Wk : Wv;
        dst = wqkvb + (size_t)which * NW4 * 4;
    }
    float4 v = ((const float4*)src)[off];
    ushort4 o;
    o.x = f2bf(v.x); o.y = f2bf(v.y); o.z = f2bf(v.z); o.w = f2bf(v.w);
    ((ushort4*)dst)[off] = o;
}

// ---- row softmax over 2048 bf16 elements, in place, one block per row -----
// Each thread owns 8 CONTIGUOUS elements: one bf16x8 load + one store.
__global__ __launch_bounds__(256) void softmax_rows(uint16_t* __restrict__ P) {
    uint16_t* row = P + (size_t)blockIdx.x * 2048;
    const int tid = threadIdx.x;
    const int w = tid >> 6, ln = tid & 63;
    bf16x8 xv = *(const bf16x8*)(&row[tid * 8]);
    float v[8];
    float m = -3.4e38f;
    #pragma unroll
    for (int i = 0; i < 8; i++) { v[i] = bf2f((uint16_t)xv[i]); m = fmaxf(m, v[i]); }
    #pragma unroll
    for (int o = 32; o >= 1; o >>= 1) m = fmaxf(m, __shfl_down(m, o, 64));
    __shared__ float smax[4], ssum[4];
    if (ln == 0) smax[w] = m;
    __syncthreads();
    m = fmaxf(fmaxf(smax[0], smax[1]), fmaxf(smax[2], smax[3]));
    float s = 0.f;
    #pragma unroll
    for (int i = 0; i < 8; i++) { v[i] = __expf(v[i] - m); s += v[i]; }
    #pragma unroll
    for (int o = 32; o >= 1; o >>= 1) s += __shfl_down(s, o, 64);
    if (ln == 0) ssum[w] = s;
    __syncthreads();
    s = ssum[0] + ssum[1] + ssum[2] + ssum[3];
    float inv = 1.f / s;
    bf16x8 ov;
    #pragma unroll
    for (int i = 0; i < 8; i++) ov[i] = (short)f2bf(v[i] * inv);
    *(bf16x8*)(&row[tid * 8]) = ov;
}

// ---- NT GEMM: C[M][N] = alpha * A[M][K] * B[N][K]^T  (bf16 in, OutT out) --
// 128 x BNt tile (BNt = 128 or 64), BK=32, 4 waves (2M x 2N), per-wave
// 64 x (BNt/2) output, mfma_f32_16x16x32_bf16.  3-stage LDS ring,
// global_load_lds w16, counted vmcnt + barrier (depth-2 prefetch; newest
// stage's loads stay in flight across the barrier).  1D grid,
// XCD-contiguous swizzle + 8x8 supertiles.  LDS chunk layout XOR-permuted
// over row-pairs (conflict-free fragment reads, verified R12):
//   p(r,q) = (r>>1)*8 + ((q + 4*(r&1)) ^ ((r>>1)&7))   [16B units]
// Optional: columns >= vcol0 written TRANSPOSED into Vt[b][col-vcol0][row]
// (V output; only used by the BNt=128 QKV instantiation).
#define BM 128
#define BK 32

template <int BNt, typename OutT>
__global__ __launch_bounds__(256) void gemm_nt(const uint16_t* __restrict__ A,
                                               const uint16_t* __restrict__ B,
                                               OutT* __restrict__ C,
                                               int gx, int gy,
                                               long lda, long ldb, long ldc,
                                               int K, float alpha,
                                               long sA, long sB, long sC,
                                               uint16_t* __restrict__ VtP,
                                               int vcol0) {
    constexpr int NB  = BNt / 32;   // B fragments per wave (4 or 2)
    constexpr int NGB = BNt / 64;   // B gll chunks per stage (2 or 1)

    // ---- XCD-contiguous swizzle + 8x8 supertile decode ----
    const int total = gridDim.x;
    const int n     = blockIdx.x;
    const int per   = total >> 3;
    const int g     = (n & 7) * per + (n >> 3);    // contiguous range per XCD
    const int pb    = gx * gy;                     // blocks per batch (z)
    const int bz    = g / pb;
    const int r     = g - bz * pb;
    const int stpr  = gx >> 3;                     // supertiles per row-band
    const int st    = r >> 6;
    const int w     = r & 63;
    const int sty   = st / stpr;
    const int stx   = st - sty * stpr;
    const int bx    = (stx << 3) + (w & 7);
    const int by    = (sty << 3) + (w >> 3);

    A += (long)bz * sA;
    B += (long)bz * sB;
    C += (long)bz * sC;

    __shared__ uint16_t As[3][BM * BK];    // 3 x 8 KB
    __shared__ uint16_t Bs[3][BNt * BK];   // 3 x 8 KB | 3 x 4 KB

    const int tid  = threadIdx.x;
    const int m0   = by * BM;
    const int n0   = bx * BNt;
    const int wave = tid >> 6;
    const int lane = tid & 63;
    const int quad = lane >> 4;
    const int l16  = lane & 15;
    const int wr   = (wave >> 1) * 64;         // wave row offset in tile
    const int wc   = (wave & 1) * (BNt / 2);   // wave col offset in tile

    // ---- staging: LDS dest is tid-linear (chunk p = tid [, tid+256]); the
    // GLOBAL source is the inverse permutation of p(r,q):
    //   e = (p&7) ^ ((p>>3)&7);  srow = 2*(p>>3)+(e>>2);  scol = (e&3)*8.
    const int e_st = (tid & 7) ^ ((tid >> 3) & 7);
    const int srow = ((tid >> 3) << 1) | (e_st >> 2);   // 0..63
    const int scol = (e_st & 3) << 3;                   // 0,8,16,24
    const uint16_t* Ag = A + (long)(m0 + srow) * lda + scol;
    const uint16_t* Bg = B + (long)(n0 + srow) * ldb + scol;
    const long rsA = 64 * lda;
    const long rsB = 64 * ldb;
    const int so0 = tid * 8;              // chunk p = tid        (rows 0-63)
    const int so1 = tid * 8 + 2048;       // chunk p = tid + 256  (rows 64-127)

    const int nk = K / BK;

    // prologue: prefetch tiles 0 and 1 into slots 0 and 1
    gll16(Ag,       &As[0][so0]);
    gll16(Ag + rsA, &As[0][so1]);
    gll16(Bg,       &Bs[0][so0]);
    if constexpr (NGB == 2) gll16(Bg + rsB, &Bs[0][so1]);
    Ag += BK; Bg += BK;
    gll16(Ag,       &As[1][so0]);
    gll16(Ag + rsA, &As[1][so1]);
    gll16(Bg,       &Bs[1][so0]);
    if constexpr (NGB == 2) gll16(Bg + rsB, &Bs[1][so1]);
    Ag += BK; Bg += BK;

    // ---- fragment-read offset (permuted): for row R = base + i*16 + l16,
    // chunk q = quad:  elem = base*32 + i*512 + h*64 + ((quad+4*sub)^h)*8,
    // h = l16>>1, sub = l16&1.  (base/2 and i*8 are 0 mod 8 -> XOR term
    // depends only on quad,l16.)
    const int h = l16 >> 1;
    const int laneOff = h * 64 + (((quad + ((l16 & 1) << 2)) ^ h) << 3);

    f32x4 acc[4][NB] = {};
    int cur = 0, pf = 2;

    for (int k = 0; k < nk; ++k) {
        // retire only the tile we are about to consume (its loads are the
        // oldest); keep the newest stage's loads in flight across the barrier.
        if (k < nk - 1) {
            if constexpr (NGB == 2)
                asm volatile("s_waitcnt vmcnt(4)\n\ts_barrier" ::: "memory");
            else
                asm volatile("s_waitcnt vmcnt(3)\n\ts_barrier" ::: "memory");
        } else {
            asm volatile("s_waitcnt vmcnt(0)\n\ts_barrier" ::: "memory");
        }

        if (k + 2 < nk) {
            gll16(Ag,       &As[pf][so0]);
            gll16(Ag + rsA, &As[pf][so1]);
            gll16(Bg,       &Bs[pf][so0]);
            if constexpr (NGB == 2) gll16(Bg + rsB, &Bs[pf][so1]);
            Ag += BK; Bg += BK;
        }

        const uint16_t* Ac = As[cur];
        const uint16_t* Bc = Bs[cur];
        bf16x8 af[4], bfr[NB];
        #pragma unroll
        for (int i = 0; i < 4; i++)
            af[i] = *(const bf16x8*)(&Ac[wr * 32 + i * 512 + laneOff]);
        #pragma unroll
        for (int j = 0; j < NB; j++)
            bfr[j] = *(const bf16x8*)(&Bc[wc * 32 + j * 512 + laneOff]);
        #pragma unroll
        for (int i = 0; i < 4; i++)
            #pragma unroll
            for (int j = 0; j < NB; j++)
                acc[i][j] = __builtin_amdgcn_mfma_f32_16x16x32_bf16(af[i], bfr[j], acc[i][j], 0, 0, 0);

        cur = (cur == 2) ? 0 : cur + 1;
        pf  = (pf  == 2) ? 0 : pf + 1;
    }

    // ---- epilogue: C/D layout col = lane&15, row = quad*4 + reg ----
    if (VtP && n0 >= vcol0) {
        // V region: write transposed, Vt[b][e][s], e = col - vcol0,
        // b = row>>11, s = row&2047. 4 consecutive rows (r4) per lane are
        // contiguous in s -> one packed ushort4 (8 B) store per (i,j).
        #pragma unroll
        for (int i = 0; i < 4; i++) {
            const int row0 = m0 + wr + i * 16 + quad * 4;
            const int b    = row0 >> 11;
            const int s    = row0 & 2047;
            #pragma unroll
            for (int j = 0; j < NB; j++) {
                const int e = n0 + wc + j * 16 + l16 - vcol0;
                ushort4 o;
                o.x = f2bf(acc[i][j][0]);
                o.y = f2bf(acc[i][j][1]);
                o.z = f2bf(acc[i][j][2]);
                o.w = f2bf(acc[i][j][3]);
                *(ushort4*)(VtP + ((long)b * 1024 + e) * 2048 + s) = o;
            }
        }
    } else {
        #pragma unroll
        for (int i = 0; i < 4; i++) {
            #pragma unroll
            for (int j = 0; j < NB; j++) {
                #pragma unroll
                for (int r4 = 0; r4 < 4; r4++) {
                    int row = m0 + wr + i * 16 + quad * 4 + r4;
                    int col = n0 + wc + j * 16 + l16;
                    float val = acc[i][j][r4] * alpha;
                    if constexpr (sizeof(OutT) == 2)
                        C[(long)row * ldc + col] = f2bf(val);
                    else
                        C[(long)row * ldc + col] = val;
                }
            }
        }
    }
}

// ---------------------------------------------------------------------------
extern "C" void kernel_launch(void* const* d_in, const int* in_sizes, int n_in,
                              void* d_out, int out_size, void* d_ws, size_t ws_size,
                              hipStream_t stream) {
    const float* x  = (const float*)d_in[0];
    const float* Wq = (const float*)d_in[1];
    const float* Wk = (const float*)d_in[2];
    const float* Wv = (const float*)d_in[3];
    float* out = (float*)d_out;

    const int Bn = 4, S = 2048, E = 1024;
    const long MS = (long)Bn * S;              // 8192 total rows
    const int  N3 = 3 * E;                     // 3072

    // workspace layout (bf16)
    char* ws = (char*)d_ws;
    uint16_t* xb    = (uint16_t*)ws;  ws += (size_t)MS * E * 2;        // 16 MB
    uint16_t* wqkvb = (uint16_t*)ws;  ws += (size_t)N3 * E * 2;        //  6 MB
    uint16_t* QKb   = (uint16_t*)ws;  ws += (size_t)MS * 2048 * 2;     // 32 MB (Q|K, ld=2048)
    uint16_t* Vt    = (uint16_t*)ws;  ws += (size_t)Bn * E * S * 2;    // 16 MB
    uint16_t* Pb    = (uint16_t*)ws;  ws += (size_t)Bn * S * S * 2;    // 32 MB

    dim3 blk(256);

    // 1) fused cast to bf16 (x + stacked [Wq;Wk;Wv])
    {
        int NX4 = (int)(MS * E / 4);            // 2097152
        int NW4 = E * E / 4;                    // 262144
        int tot = NX4 + 3 * NW4;
        cast_all<<<dim3((tot + 255) / 256), blk, 0, stream>>>(
            x, Wq, Wk, Wv, xb, wqkvb, NX4, NW4);
    }

    // 2) fused QKV: cols [0,2048) -> QKb (ld 2048); cols [2048,3072) -> Vt
    //    transposed (Vt[b][e][s]).  128x128 tiles: 24 x 64 = 1536 blocks
    //    (6/CU, 3 resident -- best measured at 715 TF).
    {
        int gx = N3 / 128, gy = (int)(MS / BM);
        gemm_nt<128, uint16_t><<<dim3(gx * gy), blk, 0, stream>>>(
            xb, wqkvb, QKb, gx, gy, E, E, 2048, E, 1.f, 0, 0, 0,
            Vt, 2048);
    }

    // 3) scores = (Q K^T) / sqrt(E) per batch, bf16 out.
    //    128x64 tiles: 32 x 16 x 4 = 2048 blocks = 2 exact rounds at 4/CU.
    {
        int gx = S / 64, gy = S / BM;
        gemm_nt<64, uint16_t><<<dim3(gx * gy * Bn), blk, 0, stream>>>(
            QKb, QKb + 1024, Pb, gx, gy, 2048, 2048, S, E, 0.03125f,
            (long)S * 2048, (long)S * 2048, (long)S * S,
            nullptr, 0);
    }

    // 4) softmax rows in place (4*2048 rows of 2048)
    softmax_rows<<<dim3(Bn * S), blk, 0, stream>>>(Pb);

    // 5) out = P * Vt^T  (M=2048, N=1024, K=2048 per batch), fp32 out.
    //    128x64 tiles: 16 x 16 x 4 = 1024 blocks = 1 exact round at 4/CU.
    {
        int gx = E / 64, gy = S / BM;
        gemm_nt<64, float><<<dim3(gx * gy * Bn), blk, 0, stream>>>(
            Pb, Vt, out, gx, gy, S, S, E, S, 1.f,
            (long)S * S, (long)E * S, (long)S * E,
            nullptr, 0);
    }
}